// Round 4
// baseline (386.845 us; speedup 1.0000x reference)
//
#include <hip/hip_runtime.h>
#include <hip/hip_bf16.h>

#define N_S 16384
#define LL 10
#define DD 256

typedef __bf16 bf16;
typedef __attribute__((ext_vector_type(8))) __bf16 bf16x8_t;
typedef __attribute__((ext_vector_type(4))) __bf16 bf16x4_t;
typedef __attribute__((ext_vector_type(4))) float f32x4_t;

// cos with explicit revolution reduction (v_cos_f32 takes revolutions)
__device__ __forceinline__ float fast_cos(float x) {
    float r = x * 0.15915494309189535f;   // x / (2*pi)
    r = r - rintf(r);                     // reduce to [-0.5, 0.5]
    return __builtin_amdgcn_cosf(r);
}

// ---------------------------------------------------------------------------
// K0: precompute factored weights (MFMA B-fragment packed) + bias folds.
// Split A-blocks / C-blocks to halve per-thread serial MAC depth; unroll 16
// keeps ~16 L2 loads in flight.
//   Acat[kk][nn] (K=256,N=512): A_h = wq_h^T @ wk_h,  nn = h*256+j
//   Ccat[kk][oo] (K=512,N=256): C_h[i,o] = sum_d wv_h[d,i] * w_out[o, h*128+d]
// ---------------------------------------------------------------------------
__global__ __launch_bounds__(256) void k_pre(
    const float* __restrict__ w_in, const float* __restrict__ b_in,
    const float* __restrict__ w_out, const float* __restrict__ b_out,
    bf16* __restrict__ Apk, bf16* __restrict__ Cpk,
    float* __restrict__ u, float* __restrict__ p,
    float* __restrict__ c2, float* __restrict__ dvec)
{
    const int bid = blockIdx.x;
    const int tid = threadIdx.x;
    if (bid < 512) {
        // ----- Acat element (kk, nn): kk uniform per block, nn = 256*(bid&1)+tid
        const int g = bid * 256 + tid;
        const int kk = g >> 9;          // 0..255
        const int nn = g & 511;         // 0..511
        const int h = nn >> 8;
        const int j = nn & 255;
        const float* wq = w_in + (size_t)(h * 128) * 256;
        const float* wk = w_in + (size_t)(256 + h * 128) * 256;
        float s = 0.f;
        #pragma unroll 16
        for (int d = 0; d < 128; ++d)
            s += wq[d * 256 + kk] * wk[d * 256 + j];
        // pack into B-fragment order for fused phase 1 (K=256 -> 8 ksteps)
        const int lane = (((kk & 31) >> 3) << 4) + (nn & 15);
        const int idx = ((((nn >> 4) * 8 + (kk >> 5)) * 64 + lane) << 3) + (kk & 7);
        Apk[idx] = (bf16)s;
    } else if (bid < 1024) {
        // ----- Ccat element (kk2, oo): oo uniform per block
        const int g = (bid - 512) * 256 + tid;
        const int oo = g >> 9;          // 0..255
        const int kk2 = g & 511;        // 0..511
        const int h = kk2 >> 8;
        const int i = kk2 & 255;
        const float* wv = w_in + (size_t)(512 + h * 128) * 256;
        float s = 0.f;
        #pragma unroll 16
        for (int d = 0; d < 128; ++d)
            s += wv[d * 256 + i] * w_out[oo * 256 + h * 128 + d];
        // pack for fused phase 3 (K=512 -> 16 ksteps)
        const int lane = (((kk2 & 31) >> 3) << 4) + (oo & 15);
        const int idx = ((((oo >> 4) * 16 + (kk2 >> 5)) * 64 + lane) << 3) + (kk2 & 7);
        Cpk[idx] = (bf16)s;
    } else {
        // small bias-fold vectors (exact handling; zeros for this setup)
        for (int j = tid; j < 512; j += 256) {
            const int h = j >> 8; const int jj = j & 255;
            float s = 0.f;
            #pragma unroll 16
            for (int d = 0; d < 128; ++d)
                s += b_in[h * 128 + d] * w_in[(size_t)(256 + h * 128 + d) * 256 + jj];
            u[j] = s;
        }
        for (int i = tid; i < 512; i += 256) {
            const int h = i >> 8; const int ii = i & 255;
            float s = 0.f;
            #pragma unroll 16
            for (int d = 0; d < 128; ++d)
                s += w_in[(size_t)(h * 128 + d) * 256 + ii] * b_in[256 + h * 128 + d];
            p[i] = s;
        }
        if (tid < 2) {
            float s = 0.f;
            #pragma unroll 16
            for (int d = 0; d < 128; ++d)
                s += b_in[tid * 128 + d] * b_in[256 + tid * 128 + d];
            c2[tid] = s;
        }
        if (tid < 256) {
            float s = b_out[tid];
            #pragma unroll 16
            for (int t = 0; t < 256; ++t)
                s += b_in[512 + t] * w_out[tid * 256 + t];
            dvec[tid] = s;
        }
    }
}

// ---------------------------------------------------------------------------
// Fused: per block, 32 samples. Three phases over an LDS G/Y tile:
//   P1: G[32][512] = m_last @ Acat + u      (MFMA, B from L2-resident Apk)
//   P2: per-sample attention (wave owns 8 samples), Y overwrites G in LDS
//   P3: out[32][256] = Y @ Ccat + dvec      (MFMA, A from LDS, B from Cpk)
// G/Y never touch HBM; m_last read once; Apk/Cpk L2-resident (256 KB each).
// ---------------------------------------------------------------------------
__global__ __launch_bounds__(256, 4) void k_fused(
    const float* __restrict__ messages, const float* __restrict__ timestamps,
    const float* __restrict__ w_time, const float* __restrict__ b_time,
    const int* __restrict__ lengths,
    const bf16* __restrict__ Apk, const bf16* __restrict__ Cpk,
    const float* __restrict__ u, const float* __restrict__ p,
    const float* __restrict__ c2, const float* __restrict__ dvec,
    float* __restrict__ out)
{
    __shared__ __align__(16) bf16 Gs[32][520];   // 33,280 B; +8 pad per row

    const int tid = threadIdx.x;
    const int lane = tid & 63;
    const int wid = tid >> 6;          // 0..3
    const int r16 = lane & 15;
    const int q4 = lane >> 4;
    const int n0 = blockIdx.x * 32;    // first sample of this block

    // ================= phase 1: G = m_last @ Acat + u  (M=32,N=512,K=256)
    {
        const int wr = wid >> 1;       // row group: 16 rows
        const int wc = wid & 1;        // col group: 256 cols
        f32x4_t acc[16];
        #pragma unroll
        for (int nt = 0; nt < 16; ++nt) acc[nt] = (f32x4_t)(0.f);

        const int arow = n0 + wr * 16 + r16;
        const float* abase = messages + (size_t)arow * (LL * DD) + (LL - 1) * DD + q4 * 8;
        #pragma unroll
        for (int ks = 0; ks < 8; ++ks) {
            f32x4_t lo = *(const f32x4_t*)(abase + ks * 32);
            f32x4_t hi = *(const f32x4_t*)(abase + ks * 32 + 4);
            bf16x8_t a;
            a[0] = (bf16)lo[0]; a[1] = (bf16)lo[1]; a[2] = (bf16)lo[2]; a[3] = (bf16)lo[3];
            a[4] = (bf16)hi[0]; a[5] = (bf16)hi[1]; a[6] = (bf16)hi[2]; a[7] = (bf16)hi[3];
            #pragma unroll
            for (int nt = 0; nt < 16; ++nt) {
                const int nblk16 = wc * 16 + nt;
                bf16x8_t b = *(const bf16x8_t*)(Apk + (((size_t)(nblk16 * 8 + ks) * 64 + lane) << 3));
                acc[nt] = __builtin_amdgcn_mfma_f32_16x16x32_bf16(a, b, acc[nt], 0, 0, 0);
            }
        }
        #pragma unroll
        for (int nt = 0; nt < 16; ++nt) {
            const int col = wc * 256 + nt * 16 + r16;
            const float ub = u[col];
            #pragma unroll
            for (int r = 0; r < 4; ++r)
                Gs[wr * 16 + q4 * 4 + r][col] = (bf16)(acc[nt][r] + ub);
        }
    }
    __syncthreads();

    // ================= phase 2: attention; wave wid owns samples wid*8..+8
    {
        const int d0 = lane * 4;
        float wt[4], bt[4], pv0[4], pv1[4];
        *(f32x4_t*)wt = *(const f32x4_t*)(w_time + d0);
        *(f32x4_t*)bt = *(const f32x4_t*)(b_time + d0);
        *(f32x4_t*)pv0 = *(const f32x4_t*)(p + d0);
        *(f32x4_t*)pv1 = *(const f32x4_t*)(p + 256 + d0);
        const float c20 = c2[0], c21 = c2[1];
        const float scale = 0.08838834764831845f;   // 1/sqrt(128)

        #pragma unroll
        for (int i = 0; i < 8; ++i) {
            const int s = wid * 8 + i;
            const int n = n0 + s;

            float g0[4], g1[4];
            {
                bf16x4_t ga = *(const bf16x4_t*)(&Gs[s][d0]);
                bf16x4_t gb = *(const bf16x4_t*)(&Gs[s][256 + d0]);
                #pragma unroll
                for (int j = 0; j < 4; ++j) { g0[j] = (float)ga[j]; g1[j] = (float)gb[j]; }
            }
            float m9[4];
            *(f32x4_t*)m9 = *(const f32x4_t*)(messages + (size_t)n * (LL * DD) + (LL - 1) * DD + d0);

            const float* tsrow = timestamps + n * LL;
            const float tlast = tsrow[LL - 1];
            const int valid = lengths[n] + 1;       // 1..10
            const int lmin = LL - valid;            // 0..9

            // s0 = m_last . p_h + c_h  (exact bias term; zero here)
            float s0a = m9[0]*pv0[0] + m9[1]*pv0[1] + m9[2]*pv0[2] + m9[3]*pv0[3];
            float s0b = m9[0]*pv1[0] + m9[1]*pv1[1] + m9[2]*pv1[2] + m9[3]*pv1[3];
            #pragma unroll
            for (int m = 1; m < 64; m <<= 1) {
                s0a += __shfl_xor(s0a, m);
                s0b += __shfl_xor(s0b, m);
            }
            s0a += c20; s0b += c21;

            float sc0[LL], sc1[LL];
            #pragma unroll
            for (int l = 0; l < LL; ++l) {
                if (l >= lmin) {                    // wave-uniform branch
                    const float delta = tsrow[l] - tlast;
                    float pa = 0.f, pb = 0.f;
                    #pragma unroll
                    for (int j = 0; j < 4; ++j) {
                        const float te = fast_cos(delta * wt[j] + bt[j]);
                        pa += g0[j] * te;
                        pb += g1[j] * te;
                    }
                    #pragma unroll
                    for (int m = 1; m < 64; m <<= 1) {
                        pa += __shfl_xor(pa, m);
                        pb += __shfl_xor(pb, m);
                    }
                    sc0[l] = (pa + s0a) * scale;
                    sc1[l] = (pb + s0b) * scale;
                } else {
                    sc0[l] = -1e30f;
                    sc1[l] = -1e30f;
                }
            }

            float mx0 = sc0[0], mx1 = sc1[0];
            #pragma unroll
            for (int l = 1; l < LL; ++l) {
                mx0 = fmaxf(mx0, sc0[l]);
                mx1 = fmaxf(mx1, sc1[l]);
            }
            float w0[LL], w1[LL];
            float den0 = 0.f, den1 = 0.f;
            #pragma unroll
            for (int l = 0; l < LL; ++l) {
                w0[l] = (l >= lmin) ? __expf(sc0[l] - mx0) : 0.f;
                w1[l] = (l >= lmin) ? __expf(sc1[l] - mx1) : 0.f;
                den0 += w0[l];
                den1 += w1[l];
            }
            const float inv0 = 1.f / den0, inv1 = 1.f / den1;

            float y0[4] = {0.f,0.f,0.f,0.f}, y1[4] = {0.f,0.f,0.f,0.f};
            #pragma unroll
            for (int l = 0; l < LL; ++l) {
                if (l >= lmin) {                    // skip masked rows: no load
                    float mv[4];
                    if (l == LL - 1) {
                        mv[0]=m9[0]; mv[1]=m9[1]; mv[2]=m9[2]; mv[3]=m9[3];
                    } else {
                        *(f32x4_t*)mv = *(const f32x4_t*)(messages + (size_t)n * (LL * DD) + l * DD + d0);
                    }
                    const float a0 = w0[l] * inv0, a1 = w1[l] * inv1;
                    #pragma unroll
                    for (int j = 0; j < 4; ++j) {
                        y0[j] += a0 * mv[j];
                        y1[j] += a1 * mv[j];
                    }
                }
            }

            // Y overwrites the G row (wave-private row; no barrier needed here)
            bf16x4_t v0, v1;
            v0[0]=(bf16)y0[0]; v0[1]=(bf16)y0[1]; v0[2]=(bf16)y0[2]; v0[3]=(bf16)y0[3];
            v1[0]=(bf16)y1[0]; v1[1]=(bf16)y1[1]; v1[2]=(bf16)y1[2]; v1[3]=(bf16)y1[3];
            *(bf16x4_t*)(&Gs[s][d0]) = v0;
            *(bf16x4_t*)(&Gs[s][256 + d0]) = v1;
        }
    }
    __syncthreads();

    // ================= phase 3: out = Y @ Ccat + dvec  (M=32,N=256,K=512)
    {
        const int wr2 = wid >> 1;      // row group: 16 rows
        const int wc2 = wid & 1;       // col group: 128 cols
        f32x4_t acc2[8];
        #pragma unroll
        for (int nt = 0; nt < 8; ++nt) acc2[nt] = (f32x4_t)(0.f);

        #pragma unroll
        for (int ks = 0; ks < 16; ++ks) {
            bf16x8_t a = *(const bf16x8_t*)(&Gs[wr2 * 16 + r16][ks * 32 + q4 * 8]);
            #pragma unroll
            for (int nt = 0; nt < 8; ++nt) {
                const int nblk16 = wc2 * 8 + nt;
                bf16x8_t b = *(const bf16x8_t*)(Cpk + (((size_t)(nblk16 * 16 + ks) * 64 + lane) << 3));
                acc2[nt] = __builtin_amdgcn_mfma_f32_16x16x32_bf16(a, b, acc2[nt], 0, 0, 0);
            }
        }
        #pragma unroll
        for (int nt = 0; nt < 8; ++nt) {
            const int col = wc2 * 128 + nt * 16 + r16;
            const float db = dvec[col];
            #pragma unroll
            for (int r = 0; r < 4; ++r) {
                const int row = n0 + wr2 * 16 + q4 * 4 + r;
                out[(size_t)row * 256 + col] = acc2[nt][r] + db;
            }
        }
    }
}

// ---------------------------------------------------------------------------
extern "C" void kernel_launch(void* const* d_in, const int* in_sizes, int n_in,
                              void* d_out, int out_size, void* d_ws, size_t ws_size,
                              hipStream_t stream) {
    const float* messages   = (const float*)d_in[0];
    const float* timestamps = (const float*)d_in[1];
    const float* w_time     = (const float*)d_in[2];
    const float* b_time     = (const float*)d_in[3];
    const float* w_in       = (const float*)d_in[4];
    const float* b_in       = (const float*)d_in[5];
    const float* w_out      = (const float*)d_in[6];
    const float* b_out      = (const float*)d_in[7];
    const int*   lengths    = (const int*)d_in[8];
    float* out = (float*)d_out;

    char* ws = (char*)d_ws;
    bf16*  Apk  = (bf16*)(ws);                 // 256 KiB
    bf16*  Cpk  = (bf16*)(ws + 262144);        // 256 KiB
    float* u    = (float*)(ws + 524288);       // 2 KiB
    float* p    = (float*)(ws + 526336);       // 2 KiB
    float* c2   = (float*)(ws + 528384);       // 8 B
    float* dvec = (float*)(ws + 528448);       // 1 KiB

    k_pre<<<dim3(1025), dim3(256), 0, stream>>>(w_in, b_in, w_out, b_out,
                                                Apk, Cpk, u, p, c2, dvec);
    k_fused<<<dim3(512), dim3(256), 0, stream>>>(messages, timestamps, w_time, b_time,
                                                 lengths, Apk, Cpk, u, p, c2, dvec, out);
}

// Round 5
// 318.683 us; speedup vs baseline: 1.2139x; 1.2139x over previous
//
#include <hip/hip_runtime.h>
#include <hip/hip_bf16.h>

#define N_S 16384
#define LL 10
#define DD 256

typedef __bf16 bf16;
typedef __attribute__((ext_vector_type(8))) __bf16 bf16x8_t;
typedef __attribute__((ext_vector_type(4))) __bf16 bf16x4_t;
typedef __attribute__((ext_vector_type(4))) float f32x4_t;

// cos with explicit revolution reduction (v_cos_f32 takes revolutions)
__device__ __forceinline__ float fast_cos(float x) {
    float r = x * 0.15915494309189535f;   // x / (2*pi)
    r = r - rintf(r);                     // reduce to [-0.5, 0.5]
    return __builtin_amdgcn_cosf(r);
}

// ---------------------------------------------------------------------------
// K0: precompute factored weights (MFMA B-fragment packed) + bias folds.
// (unchanged from round 4 — not implicated by the counters)
// ---------------------------------------------------------------------------
__global__ __launch_bounds__(256) void k_pre(
    const float* __restrict__ w_in, const float* __restrict__ b_in,
    const float* __restrict__ w_out, const float* __restrict__ b_out,
    bf16* __restrict__ Apk, bf16* __restrict__ Cpk,
    float* __restrict__ u, float* __restrict__ p,
    float* __restrict__ c2, float* __restrict__ dvec)
{
    const int bid = blockIdx.x;
    const int tid = threadIdx.x;
    if (bid < 512) {
        const int g = bid * 256 + tid;
        const int kk = g >> 9;          // 0..255
        const int nn = g & 511;         // 0..511
        const int h = nn >> 8;
        const int j = nn & 255;
        const float* wq = w_in + (size_t)(h * 128) * 256;
        const float* wk = w_in + (size_t)(256 + h * 128) * 256;
        float s = 0.f;
        #pragma unroll 16
        for (int d = 0; d < 128; ++d)
            s += wq[d * 256 + kk] * wk[d * 256 + j];
        // pack into B-fragment order for fused phase 1 (K=256 -> 8 ksteps)
        const int lane = (((kk & 31) >> 3) << 4) + (nn & 15);
        const int idx = ((((nn >> 4) * 8 + (kk >> 5)) * 64 + lane) << 3) + (kk & 7);
        Apk[idx] = (bf16)s;
    } else if (bid < 1024) {
        const int g = (bid - 512) * 256 + tid;
        const int oo = g >> 9;          // 0..255
        const int kk2 = g & 511;        // 0..511
        const int h = kk2 >> 8;
        const int i = kk2 & 255;
        const float* wv = w_in + (size_t)(512 + h * 128) * 256;
        float s = 0.f;
        #pragma unroll 16
        for (int d = 0; d < 128; ++d)
            s += wv[d * 256 + i] * w_out[oo * 256 + h * 128 + d];
        // pack for fused phase 3 (K=512 -> 16 ksteps)
        const int lane = (((kk2 & 31) >> 3) << 4) + (oo & 15);
        const int idx = ((((oo >> 4) * 16 + (kk2 >> 5)) * 64 + lane) << 3) + (kk2 & 7);
        Cpk[idx] = (bf16)s;
    } else {
        for (int j = tid; j < 512; j += 256) {
            const int h = j >> 8; const int jj = j & 255;
            float s = 0.f;
            #pragma unroll 16
            for (int d = 0; d < 128; ++d)
                s += b_in[h * 128 + d] * w_in[(size_t)(256 + h * 128 + d) * 256 + jj];
            u[j] = s;
        }
        for (int i = tid; i < 512; i += 256) {
            const int h = i >> 8; const int ii = i & 255;
            float s = 0.f;
            #pragma unroll 16
            for (int d = 0; d < 128; ++d)
                s += w_in[(size_t)(h * 128 + d) * 256 + ii] * b_in[256 + h * 128 + d];
            p[i] = s;
        }
        if (tid < 2) {
            float s = 0.f;
            #pragma unroll 16
            for (int d = 0; d < 128; ++d)
                s += b_in[tid * 128 + d] * b_in[256 + tid * 128 + d];
            c2[tid] = s;
        }
        if (tid < 256) {
            float s = b_out[tid];
            #pragma unroll 16
            for (int t = 0; t < 256; ++t)
                s += b_in[512 + t] * w_out[tid * 256 + t];
            dvec[tid] = s;
        }
    }
}

// ---------------------------------------------------------------------------
// Fused, occupancy-fixed: 16 samples/block, 1024 blocks (4 blocks/CU,
// 16 waves/CU vs round-4's 8). LDS tile 16.6 KB.
//   P1: G[16][512] = m_last @ Acat + u   (waves split 512 cols 4-ways)
//   P2: attention, wave owns 4 samples; Y overwrites G rows in LDS
//   P3: out[16][256] = Y @ Ccat + dvec   (waves split 256 cols 4-ways)
// ---------------------------------------------------------------------------
__global__ __launch_bounds__(256, 4) void k_fused(
    const float* __restrict__ messages, const float* __restrict__ timestamps,
    const float* __restrict__ w_time, const float* __restrict__ b_time,
    const int* __restrict__ lengths,
    const bf16* __restrict__ Apk, const bf16* __restrict__ Cpk,
    const float* __restrict__ u, const float* __restrict__ p,
    const float* __restrict__ c2, const float* __restrict__ dvec,
    float* __restrict__ out)
{
    __shared__ __align__(16) bf16 Gs[16][520];   // 16,640 B; +8 bf16 pad/row

    const int tid = threadIdx.x;
    const int lane = tid & 63;
    const int wid = tid >> 6;          // 0..3
    const int r16 = lane & 15;
    const int q4 = lane >> 4;
    const int n0 = blockIdx.x * 16;    // first sample of this block

    // ================= phase 1: G = m_last @ Acat + u  (M=16,N=512,K=256)
    // wave wid owns cols [wid*128, wid*128+128)
    {
        f32x4_t acc[8];
        #pragma unroll
        for (int nt = 0; nt < 8; ++nt) acc[nt] = (f32x4_t)(0.f);

        const int arow = n0 + r16;
        const float* abase = messages + (size_t)arow * (LL * DD) + (LL - 1) * DD + q4 * 8;
        #pragma unroll
        for (int ks = 0; ks < 8; ++ks) {
            f32x4_t lo = *(const f32x4_t*)(abase + ks * 32);
            f32x4_t hi = *(const f32x4_t*)(abase + ks * 32 + 4);
            bf16x8_t a;
            a[0] = (bf16)lo[0]; a[1] = (bf16)lo[1]; a[2] = (bf16)lo[2]; a[3] = (bf16)lo[3];
            a[4] = (bf16)hi[0]; a[5] = (bf16)hi[1]; a[6] = (bf16)hi[2]; a[7] = (bf16)hi[3];
            #pragma unroll
            for (int nt = 0; nt < 8; ++nt) {
                const int nblk16 = wid * 8 + nt;
                bf16x8_t b = *(const bf16x8_t*)(Apk + (((size_t)(nblk16 * 8 + ks) * 64 + lane) << 3));
                acc[nt] = __builtin_amdgcn_mfma_f32_16x16x32_bf16(a, b, acc[nt], 0, 0, 0);
            }
        }
        #pragma unroll
        for (int nt = 0; nt < 8; ++nt) {
            const int col = wid * 128 + nt * 16 + r16;
            const float ub = u[col];
            #pragma unroll
            for (int r = 0; r < 4; ++r)
                Gs[q4 * 4 + r][col] = (bf16)(acc[nt][r] + ub);
        }
    }
    __syncthreads();

    // ================= phase 2: attention; wave wid owns samples wid*4..+4
    {
        const int d0 = lane * 4;
        float wt[4], bt[4], pv0[4], pv1[4];
        *(f32x4_t*)wt = *(const f32x4_t*)(w_time + d0);
        *(f32x4_t*)bt = *(const f32x4_t*)(b_time + d0);
        *(f32x4_t*)pv0 = *(const f32x4_t*)(p + d0);
        *(f32x4_t*)pv1 = *(const f32x4_t*)(p + 256 + d0);
        const float c20 = c2[0], c21 = c2[1];
        const float scale = 0.08838834764831845f;   // 1/sqrt(128)

        #pragma unroll
        for (int i = 0; i < 4; ++i) {
            const int s = wid * 4 + i;
            const int n = n0 + s;

            float g0[4], g1[4];
            {
                bf16x4_t ga = *(const bf16x4_t*)(&Gs[s][d0]);
                bf16x4_t gb = *(const bf16x4_t*)(&Gs[s][256 + d0]);
                #pragma unroll
                for (int j = 0; j < 4; ++j) { g0[j] = (float)ga[j]; g1[j] = (float)gb[j]; }
            }
            float m9[4];
            *(f32x4_t*)m9 = *(const f32x4_t*)(messages + (size_t)n * (LL * DD) + (LL - 1) * DD + d0);

            const float* tsrow = timestamps + n * LL;
            const float tlast = tsrow[LL - 1];
            const int valid = lengths[n] + 1;       // 1..10
            const int lmin = LL - valid;            // 0..9

            // s0 = m_last . p_h + c_h  (exact bias term; zero here)
            float s0a = m9[0]*pv0[0] + m9[1]*pv0[1] + m9[2]*pv0[2] + m9[3]*pv0[3];
            float s0b = m9[0]*pv1[0] + m9[1]*pv1[1] + m9[2]*pv1[2] + m9[3]*pv1[3];
            #pragma unroll
            for (int m = 1; m < 64; m <<= 1) {
                s0a += __shfl_xor(s0a, m);
                s0b += __shfl_xor(s0b, m);
            }
            s0a += c20; s0b += c21;

            float sc0[LL], sc1[LL];
            #pragma unroll
            for (int l = 0; l < LL; ++l) {
                if (l >= lmin) {                    // wave-uniform branch
                    const float delta = tsrow[l] - tlast;
                    float pa = 0.f, pb = 0.f;
                    #pragma unroll
                    for (int j = 0; j < 4; ++j) {
                        const float te = fast_cos(delta * wt[j] + bt[j]);
                        pa += g0[j] * te;
                        pb += g1[j] * te;
                    }
                    #pragma unroll
                    for (int m = 1; m < 64; m <<= 1) {
                        pa += __shfl_xor(pa, m);
                        pb += __shfl_xor(pb, m);
                    }
                    sc0[l] = (pa + s0a) * scale;
                    sc1[l] = (pb + s0b) * scale;
                } else {
                    sc0[l] = -1e30f;
                    sc1[l] = -1e30f;
                }
            }

            float mx0 = sc0[0], mx1 = sc1[0];
            #pragma unroll
            for (int l = 1; l < LL; ++l) {
                mx0 = fmaxf(mx0, sc0[l]);
                mx1 = fmaxf(mx1, sc1[l]);
            }
            float w0[LL], w1[LL];
            float den0 = 0.f, den1 = 0.f;
            #pragma unroll
            for (int l = 0; l < LL; ++l) {
                w0[l] = (l >= lmin) ? __expf(sc0[l] - mx0) : 0.f;
                w1[l] = (l >= lmin) ? __expf(sc1[l] - mx1) : 0.f;
                den0 += w0[l];
                den1 += w1[l];
            }
            const float inv0 = 1.f / den0, inv1 = 1.f / den1;

            float y0[4] = {0.f,0.f,0.f,0.f}, y1[4] = {0.f,0.f,0.f,0.f};
            #pragma unroll
            for (int l = 0; l < LL; ++l) {
                if (l >= lmin) {                    // skip masked rows: no load
                    float mv[4];
                    if (l == LL - 1) {
                        mv[0]=m9[0]; mv[1]=m9[1]; mv[2]=m9[2]; mv[3]=m9[3];
                    } else {
                        *(f32x4_t*)mv = *(const f32x4_t*)(messages + (size_t)n * (LL * DD) + l * DD + d0);
                    }
                    const float a0 = w0[l] * inv0, a1 = w1[l] * inv1;
                    #pragma unroll
                    for (int j = 0; j < 4; ++j) {
                        y0[j] += a0 * mv[j];
                        y1[j] += a1 * mv[j];
                    }
                }
            }

            // Y overwrites the G row (wave-private row; no barrier needed here)
            bf16x4_t v0, v1;
            v0[0]=(bf16)y0[0]; v0[1]=(bf16)y0[1]; v0[2]=(bf16)y0[2]; v0[3]=(bf16)y0[3];
            v1[0]=(bf16)y1[0]; v1[1]=(bf16)y1[1]; v1[2]=(bf16)y1[2]; v1[3]=(bf16)y1[3];
            *(bf16x4_t*)(&Gs[s][d0]) = v0;
            *(bf16x4_t*)(&Gs[s][256 + d0]) = v1;
        }
    }
    __syncthreads();

    // ================= phase 3: out = Y @ Ccat + dvec  (M=16,N=256,K=512)
    // wave wid owns cols [wid*64, wid*64+64)
    {
        f32x4_t acc2[4];
        #pragma unroll
        for (int nt = 0; nt < 4; ++nt) acc2[nt] = (f32x4_t)(0.f);

        #pragma unroll
        for (int ks = 0; ks < 16; ++ks) {
            bf16x8_t a = *(const bf16x8_t*)(&Gs[r16][ks * 32 + q4 * 8]);
            #pragma unroll
            for (int nt = 0; nt < 4; ++nt) {
                const int nblk16 = wid * 4 + nt;
                bf16x8_t b = *(const bf16x8_t*)(Cpk + (((size_t)(nblk16 * 16 + ks) * 64 + lane) << 3));
                acc2[nt] = __builtin_amdgcn_mfma_f32_16x16x32_bf16(a, b, acc2[nt], 0, 0, 0);
            }
        }
        #pragma unroll
        for (int nt = 0; nt < 4; ++nt) {
            const int col = wid * 64 + nt * 16 + r16;
            const float db = dvec[col];
            #pragma unroll
            for (int r = 0; r < 4; ++r) {
                const int row = n0 + q4 * 4 + r;
                out[(size_t)row * 256 + col] = acc2[nt][r] + db;
            }
        }
    }
}

// ---------------------------------------------------------------------------
extern "C" void kernel_launch(void* const* d_in, const int* in_sizes, int n_in,
                              void* d_out, int out_size, void* d_ws, size_t ws_size,
                              hipStream_t stream) {
    const float* messages   = (const float*)d_in[0];
    const float* timestamps = (const float*)d_in[1];
    const float* w_time     = (const float*)d_in[2];
    const float* b_time     = (const float*)d_in[3];
    const float* w_in       = (const float*)d_in[4];
    const float* b_in       = (const float*)d_in[5];
    const float* w_out      = (const float*)d_in[6];
    const float* b_out      = (const float*)d_in[7];
    const int*   lengths    = (const int*)d_in[8];
    float* out = (float*)d_out;

    char* ws = (char*)d_ws;
    bf16*  Apk  = (bf16*)(ws);                 // 256 KiB
    bf16*  Cpk  = (bf16*)(ws + 262144);        // 256 KiB
    float* u    = (float*)(ws + 524288);       // 2 KiB
    float* p    = (float*)(ws + 526336);       // 2 KiB
    float* c2   = (float*)(ws + 528384);       // 8 B
    float* dvec = (float*)(ws + 528448);       // 1 KiB

    k_pre<<<dim3(1025), dim3(256), 0, stream>>>(w_in, b_in, w_out, b_out,
                                                Apk, Cpk, u, p, c2, dvec);
    k_fused<<<dim3(1024), dim3(256), 0, stream>>>(messages, timestamps, w_time, b_time,
                                                  lengths, Apk, Cpk, u, p, c2, dvec, out);
}